// Round 11
// baseline (46.835 us; speedup 1.0000x reference)
//
#include <hip/hip_runtime.h>

#define NROWS  8
#define NPIX   262144         // 512*512
#define K1_BPR 256            // compute: 1024 px/block, grid 2048
#define KC_BPR 128            // collect: 2048 px/block, grid 1024
#define HB8    256            // 8-bit histogram bins per row
#define NSALT  16             // LDS histogram replication (bank-spread)
#define SSTRIDE 257           // copy stride: bank = (salt + bin) % 32

// monotonic float->uint map (ascending float == ascending uint)
__device__ __forceinline__ unsigned int fkey(float x){
  unsigned int u = __float_as_uint(x);
  return (u & 0x80000000u) ? ~u : (u | 0x80000000u);
}

// binary softmax with a single exp
__device__ __forceinline__ void softmax2(float a0, float a1,
    float& lp0, float& lp1, float& p0, float& p1){
  float d  = a1 - a0;
  float ad = -fabsf(d);
  float e  = __expf(ad);
  float s  = 1.0f + e;
  float ls = __logf(s);
  float rs = __builtin_amdgcn_rcpf(s);
  float lpM = -ls,  lpm = ad - ls;
  float pM  = rs,   pm  = e * rs;
  bool g = (d >= 0.0f);
  lp1 = g ? lpM : lpm;  lp0 = g ? lpm : lpM;
  p1  = g ? pM  : pm;   p0  = g ? pm  : pM;
}

__device__ __forceinline__ float focal2(float tt, float lp0, float lp1,
                                        float p0, float p1){
  float q1 = 1.0f - p1, q0 = 1.0f - p0;
  return -(tt * q1 * q1 * lp1) - ((1.0f - tt) * q0 * q0 * lp0);
}

__device__ __forceinline__ unsigned kTop(const float* frp){
  return (unsigned)((1.0 - (double)(*frp)) * (double)NPIX);   // 209715
}

// parallel 256-bin select (256 threads): returns (bin, kRem-within-bin)
__device__ __forceinline__ uint2 selectBinV(unsigned v, unsigned kRem,
    unsigned* cum, unsigned* res){
  const int t = threadIdx.x;
  cum[t] = v;
  if (t == 0){ res[0] = 255u; res[1] = kRem; }
  __syncthreads();
  unsigned run = v;
  #pragma unroll
  for (int off = 1; off < 256; off <<= 1){
    unsigned add = (t >= off) ? cum[t - off] : 0u;
    __syncthreads();
    run += add;
    cum[t] = run;
    __syncthreads();
  }
  unsigned inc = cum[t], exc = inc - v;
  if (exc < kRem && inc >= kRem) { res[0] = (unsigned)t; res[1] = kRem - exc; }
  __syncthreads();
  uint2 r = make_uint2(res[0], res[1]);
  __syncthreads();
  return r;
}

// loss compute + pack + lane-salted 256-bin LDS hist, flushed as a PLAIN
// coalesced store to per-block hist (no global atomics anywhere -> no
// pre-zero dispatch needed; r8 lesson: no cross-block fences either).
// Packed word: [31:20]=key12  [19]=target  [18:0]=l3 bits (exp8+man10, rnd)
__global__ __launch_bounds__(256) void k_compute(
    const float* __restrict__ in1, const float* __restrict__ in2,
    const float* __restrict__ in3, const int* __restrict__ tgt,
    const float* __restrict__ kdwp,
    unsigned int* __restrict__ packed, unsigned int* __restrict__ bhist)
{
  __shared__ unsigned lh[NSALT * SSTRIDE];   // 16.4 KB salted histogram
  const int t = threadIdx.x;
  for (int i = t; i < NSALT * SSTRIDE; i += 256) lh[i] = 0;
  __syncthreads();

  const int blk   = blockIdx.x;
  const int row   = blk >> 8;                       // / K1_BPR
  const int chunk = (blk & (K1_BPR - 1)) * (NPIX / K1_BPR);
  const int base  = chunk + 4 * t;
  const float kdw = *kdwp;
  const float w1  = (float)(1.0 - (double)kdw);

  const size_t ro2 = (size_t)row * 2 * NPIX;
  const size_t ro1 = (size_t)row * NPIX;

  float4 x10 = *(const float4*)(in1 + ro2 + base);
  float4 x11 = *(const float4*)(in1 + ro2 + NPIX + base);
  float4 x20 = *(const float4*)(in2 + ro2 + base);
  float4 x21 = *(const float4*)(in2 + ro2 + NPIX + base);
  float4 x30 = *(const float4*)(in3 + ro2 + base);
  float4 x31 = *(const float4*)(in3 + ro2 + NPIX + base);
  int4   tg  = *(const int4*)(tgt + ro1 + base);

  float a10[4] = {x10.x, x10.y, x10.z, x10.w};
  float a11[4] = {x11.x, x11.y, x11.z, x11.w};
  float a20[4] = {x20.x, x20.y, x20.z, x20.w};
  float a21[4] = {x21.x, x21.y, x21.z, x21.w};
  float a30[4] = {x30.x, x30.y, x30.z, x30.w};
  float a31[4] = {x31.x, x31.y, x31.z, x31.w};
  int   tgv[4] = {tg.x, tg.y, tg.z, tg.w};

  const int salt = (t & (NSALT - 1)) * SSTRIDE;
  unsigned pw[4];
  #pragma unroll
  for (int j = 0; j < 4; ++j){
    float tt = (float)tgv[j];
    float lp10, lp11, p10, p11; softmax2(a10[j], a11[j], lp10, lp11, p10, p11);
    float lp20, lp21, p20, p21; softmax2(a20[j], a21[j], lp20, lp21, p20, p21);
    float lp30, lp31, p30, p31; softmax2(a30[j], a31[j], lp30, lp31, p30, p31);
    float l1 = focal2(tt, lp10, lp11, p10, p11);
    float l2 = focal2(tt, lp20, lp21, p20, p21);
    float l3 = focal2(tt, lp30, lp31, p30, p31);
    float kdl12 = p10 * (lp10 - lp20) + p11 * (lp11 - lp21);
    float kdl21 = p20 * (lp20 - lp10) + p21 * (lp21 - lp11);
    float loss  = w1 * (l1 + l2 + l3) + kdw * (kdl12 + kdl21);
    unsigned k12 = fkey(loss) >> 20;
    // l3 >= 0: keep exp8+man10, round-to-nearest via +0x1000 before shift
    unsigned lb = __float_as_uint(l3) + 0x1000u;
    pw[j] = (k12 << 20) | (((unsigned)tgv[j]) << 19) | ((lb >> 13) & 0x7FFFFu);
    atomicAdd(&lh[salt + (k12 >> 4)], 1u);     // 1 salted LDS atomic / pixel
  }
  *(uint4*)(packed + ro1 + base) = make_uint4(pw[0], pw[1], pw[2], pw[3]);

  __syncthreads();
  // reduce 16 copies (conflict-free: bank = (c+t)%32) -> plain store
  unsigned v = 0;
  #pragma unroll
  for (int c = 0; c < NSALT; ++c) v += lh[c * SSTRIDE + t];
  bhist[(size_t)blk * HB8 + t] = v;
}

// 8 blocks: sum row's 256 block-hists (L2-resident) + one selectBinV/row
__global__ __launch_bounds__(256) void k_hist(
    const unsigned int* __restrict__ bhist, const float* __restrict__ frp,
    unsigned int* __restrict__ selP8, unsigned int* __restrict__ selKrem)
{
  __shared__ unsigned cum[256];
  __shared__ unsigned res[2];
  const int t = threadIdx.x, r = blockIdx.x;
  const unsigned* bh = bhist + (size_t)r * K1_BPR * HB8;
  unsigned v = 0;
  #pragma unroll 16
  for (int b = 0; b < K1_BPR; ++b) v += bh[b * HB8 + t];
  uint2 s0 = selectBinV(v, kTop(frp), cum, res);
  if (t == 0){ selP8[r] = s0.x; selKrem[r] = s0.y; }
}

// collect: below-bin sums + per-wave 16-sub-bin stats; ALL plain stores
// (no atomics, no per-block scan -- threshold precomputed by k_hist)
__global__ __launch_bounds__(256) void k_collect(
    const unsigned int* __restrict__ packed,
    const unsigned int* __restrict__ selP8,
    float* __restrict__ pB3, unsigned int* __restrict__ pBT,
    unsigned int* __restrict__ pAT, unsigned int* __restrict__ pSub)
{
  __shared__ unsigned s_cnt[4][16];
  __shared__ float    s_l3[4][16];
  __shared__ unsigned s_tg[4][16];
  __shared__ float wf[4];
  __shared__ int   wi[8];
  const int t = threadIdx.x, lane = t & 63, wid = t >> 6;
  const int blk   = blockIdx.x;
  const int row   = blk >> 7;                       // / KC_BPR
  const int chunk = (blk & (KC_BPR - 1)) * (NPIX / KC_BPR);
  const size_t ro = (size_t)row * NPIX;
  const unsigned T8 = selP8[row];
  if (t < 64){
    s_cnt[t >> 4][t & 15] = 0; s_l3[t >> 4][t & 15] = 0.0f;
    s_tg[t >> 4][t & 15] = 0;
  }
  __syncthreads();

  float b3 = 0.0f; int bt = 0, at = 0;
  #pragma unroll
  for (int it = 0; it < 2; ++it){
    int base = chunk + it * 1024 + 4 * t;
    uint4 w = *(const uint4*)(packed + ro + base);
    unsigned a[4] = {w.x, w.y, w.z, w.w};
    #pragma unroll
    for (int j = 0; j < 4; ++j){
      unsigned k8 = a[j] >> 24;
      float l3 = __uint_as_float((a[j] & 0x7FFFFu) << 13);
      int   tv = (int)((a[j] >> 19) & 1u);
      at += tv;
      if (k8 < T8){ b3 += l3; bt += tv; }
      else if (k8 == T8){
        unsigned sub = (a[j] >> 20) & 15u;     // key12 refinement
        atomicAdd(&s_cnt[wid][sub], 1u);       // per-wave copy: 4x less clash
        atomicAdd(&s_l3[wid][sub], l3);
        if (tv) atomicAdd(&s_tg[wid][sub], 1u);
      }
    }
  }
  #pragma unroll
  for (int o = 32; o; o >>= 1){
    b3 += __shfl_down(b3, o); bt += __shfl_down(bt, o); at += __shfl_down(at, o);
  }
  if (lane == 0){ wf[wid] = b3; wi[wid] = bt; wi[4 + wid] = at; }
  __syncthreads();
  if (t < 16){
    unsigned* ps = pSub + (size_t)blk * 48;
    ps[t]      = s_cnt[0][t] + s_cnt[1][t] + s_cnt[2][t] + s_cnt[3][t];
    float l    = s_l3[0][t] + s_l3[1][t] + s_l3[2][t] + s_l3[3][t];
    ps[16 + t] = __float_as_uint(l);
    ps[32 + t] = s_tg[0][t] + s_tg[1][t] + s_tg[2][t] + s_tg[3][t];
  }
  if (t == 0){
    pB3[blk] = wf[0] + wf[1] + wf[2] + wf[3];
    pBT[blk] = (unsigned)(wi[0] + wi[1] + wi[2] + wi[3]);
    pAT[blk] = (unsigned)(wi[4] + wi[5] + wi[6] + wi[7]);
  }
}

// single block: reduce sub stats per (row,sub), tie fractions, final sums
__global__ __launch_bounds__(256) void k_final(
    const unsigned int* __restrict__ selKrem, const float* __restrict__ frp,
    const unsigned int* __restrict__ pSub,
    const float* __restrict__ pB3, const unsigned int* __restrict__ pBT,
    const unsigned int* __restrict__ pAT, float* __restrict__ out)
{
  __shared__ unsigned sub_cnt[NROWS][16];
  __shared__ double   sub_l3[NROWS][16];
  __shared__ unsigned sub_tg[NROWS][16];
  __shared__ double dd[12];
  const int t = threadIdx.x, lane = t & 63, wid = t >> 6;
  const unsigned k0 = kTop(frp);

  if (t < 128){
    int r = t >> 4, s = t & 15;
    unsigned c = 0, g = 0; double l = 0.0;
    #pragma unroll 8
    for (int b = 0; b < KC_BPR; ++b){
      const unsigned* ps = pSub + (size_t)(r * KC_BPR + b) * 48;
      c += ps[s];
      l += (double)__uint_as_float(ps[16 + s]);
      g += ps[32 + s];
    }
    sub_cnt[r][s] = c; sub_l3[r][s] = l; sub_tg[r][s] = g;
  }
  __syncthreads();

  // per-row tie resolution (16 sub-bins, frac-weighted crossing bin)
  double tie3 = 0.0, tieT = 0.0;
  if (t < NROWS){
    const int r = t;
    const unsigned kRem = selKrem[r];
    unsigned cum2 = 0;
    for (int s2 = 0; s2 < 16; ++s2){
      unsigned c = sub_cnt[r][s2];
      if (c){
        unsigned take = 0;
        if (kRem > cum2){
          unsigned avail = kRem - cum2;
          take = (avail < c) ? avail : c;
        }
        if (take){
          double fr = (double)take / (double)c;
          tie3 += fr * sub_l3[r][s2];
          tieT += fr * (double)sub_tg[r][s2];
        }
        cum2 += c;
      }
    }
  }

  double S3 = tie3, ST = tieT, TT = 0.0;
  for (int i = t; i < NROWS * KC_BPR; i += 256){
    S3 += (double)pB3[i]; ST += (double)pBT[i]; TT += (double)pAT[i];
  }
  #pragma unroll
  for (int o = 32; o; o >>= 1){
    S3 += __shfl_down(S3, o); ST += __shfl_down(ST, o); TT += __shfl_down(TT, o);
  }
  if (lane == 0){ dd[wid] = S3; dd[4 + wid] = ST; dd[8 + wid] = TT; }
  __syncthreads();
  if (t == 0){
    double s0 = dd[0] + dd[1] + dd[2] + dd[3];
    double s1 = dd[4] + dd[5] + dd[6] + dd[7];
    double st = dd[8] + dd[9] + dd[10] + dd[11];
    out[0] = (float)(s0 / ((double)NROWS * (double)k0));
    out[1] = (float)(s1 / st);
  }
}

extern "C" void kernel_launch(void* const* d_in, const int* in_sizes, int n_in,
                              void* d_out, int out_size, void* d_ws, size_t ws_size,
                              hipStream_t stream)
{
  const float* in1  = (const float*)d_in[0];
  const float* in2  = (const float*)d_in[1];
  const float* in3  = (const float*)d_in[2];
  const int*   tgt  = (const int*)d_in[3];
  const float* frp  = (const float*)d_in[4];
  const float* kdwp = (const float*)d_in[5];
  float* out = (float*)d_out;
  char*  ws  = (char*)d_ws;

  const size_t off_packed = 0;                                      // 8 MB
  const size_t off_bhist  = (size_t)NROWS * NPIX * 4;
  const size_t off_sel    = off_bhist + (size_t)NROWS * K1_BPR * HB8 * 4;
  const size_t off_pB3    = (off_sel + 2 * NROWS * 4 + 255) & ~(size_t)255;
  const size_t off_pBT    = off_pB3 + (size_t)NROWS * KC_BPR * 4;
  const size_t off_pAT    = off_pBT + (size_t)NROWS * KC_BPR * 4;
  const size_t off_pSub   = off_pAT + (size_t)NROWS * KC_BPR * 4;

  unsigned int* packed = (unsigned int*)(ws + off_packed);
  unsigned int* bhist  = (unsigned int*)(ws + off_bhist);
  unsigned int* selP8  = (unsigned int*)(ws + off_sel);
  unsigned int* selKr  = selP8 + NROWS;
  float*        pB3    = (float*)(ws + off_pB3);
  unsigned int* pBT    = (unsigned int*)(ws + off_pBT);
  unsigned int* pAT    = (unsigned int*)(ws + off_pAT);
  unsigned int* pSub   = (unsigned int*)(ws + off_pSub);

  k_compute<<<NROWS * K1_BPR, 256, 0, stream>>>(in1, in2, in3, tgt, kdwp,
                                                packed, bhist);
  k_hist<<<NROWS, 256, 0, stream>>>(bhist, frp, selP8, selKr);
  k_collect<<<NROWS * KC_BPR, 256, 0, stream>>>(packed, selP8,
                                                pB3, pBT, pAT, pSub);
  k_final<<<1, 256, 0, stream>>>(selKr, frp, pSub, pB3, pBT, pAT, out);
}